// Round 5
// baseline (553.192 us; speedup 1.0000x reference)
//
#include <hip/hip_runtime.h>
#include <hip/hip_fp16.h>
#include <cfloat>
#include <climits>

// VectorQuantizer2: z [32,2048,256] fp32, codebook [4096,256] fp32.
#define D     256
#define NE    4096
#define MT    64       // rows per block (stageA and stageB)
#define NSPLITB 8      // stageB K-split factor (512 codes per y-block)
// DELTA covers worst-case np fp32 envelope (2*4.6e-5) + fp16 single-pass dot
// worst bound (~5e-5 score) + bf16-Bnp quantization (~3e-8, negligible).
// DELTA >= 2*E_singlepass, the condition under which the single-pass stageB
// rescan is sufficient (see K4).
#define DELTA     1.5e-4f
#define CAND_CAP  131072

typedef _Float16 f16x8 __attribute__((ext_vector_type(8)));
typedef __attribute__((ext_vector_type(4))) float f32x4;

// counted-vmcnt barrier: keep prefetch in flight across the barrier (T4).
// Fused in ONE asm so no memory op can slip between wait and barrier.
// sched_barrier(0) after it pins every LDS read AFTER the wait (rule-18 class).
#define SYNC(n) do { \
    asm volatile("s_waitcnt vmcnt(" #n ")\n\ts_barrier" ::: "memory"); \
    __builtin_amdgcn_sched_barrier(0); \
} while (0)

// ---------------------------------------------------------------------------
// numpy-bit-exact fp32 helpers. __fmul_rn/__fadd_rn are contraction barriers.
__device__ __forceinline__ float np_block128_sq(const float* __restrict__ p) {
    float r[8];
    #pragma unroll
    for (int j = 0; j < 8; ++j) r[j] = __fmul_rn(p[j], p[j]);
    #pragma unroll
    for (int i = 8; i < 128; i += 8)
        #pragma unroll
        for (int j = 0; j < 8; ++j) r[j] = __fadd_rn(r[j], __fmul_rn(p[i + j], p[i + j]));
    return __fadd_rn(__fadd_rn(__fadd_rn(r[0], r[1]), __fadd_rn(r[2], r[3])),
                     __fadd_rn(__fadd_rn(r[4], r[5]), __fadd_rn(r[6], r[7])));
}
__device__ __forceinline__ float np_sumsq256(const float* __restrict__ p) {
    return __fadd_rn(np_block128_sq(p), np_block128_sq(p + 128));
}
// np.einsum('nd,kd->nk', optimize=False) dot: SSE 4-lane, no FMA, 16/iter,
// chained muladd order p3,p2,p1,p0, SSE3 hadd (v0+v1)+(v2+v3).
__device__ __forceinline__ float np_einsum_dot256(const float* __restrict__ zr,
                                                  const float* __restrict__ er) {
    float v0 = 0.f, v1 = 0.f, v2 = 0.f, v3 = 0.f;
    for (int t = 0; t < 256; t += 16) {
        float4 a0 = *(const float4*)(zr + t);
        float4 a1 = *(const float4*)(zr + t + 4);
        float4 a2 = *(const float4*)(zr + t + 8);
        float4 a3 = *(const float4*)(zr + t + 12);
        float4 b0 = *(const float4*)(er + t);
        float4 b1 = *(const float4*)(er + t + 4);
        float4 b2 = *(const float4*)(er + t + 8);
        float4 b3 = *(const float4*)(er + t + 12);
        v0 = __fadd_rn(v0, __fmul_rn(a3.x, b3.x));
        v1 = __fadd_rn(v1, __fmul_rn(a3.y, b3.y));
        v2 = __fadd_rn(v2, __fmul_rn(a3.z, b3.z));
        v3 = __fadd_rn(v3, __fmul_rn(a3.w, b3.w));
        v0 = __fadd_rn(v0, __fmul_rn(a2.x, b2.x));
        v1 = __fadd_rn(v1, __fmul_rn(a2.y, b2.y));
        v2 = __fadd_rn(v2, __fmul_rn(a2.z, b2.z));
        v3 = __fadd_rn(v3, __fmul_rn(a2.w, b2.w));
        v0 = __fadd_rn(v0, __fmul_rn(a1.x, b1.x));
        v1 = __fadd_rn(v1, __fmul_rn(a1.y, b1.y));
        v2 = __fadd_rn(v2, __fmul_rn(a1.z, b1.z));
        v3 = __fadd_rn(v3, __fmul_rn(a1.w, b1.w));
        v0 = __fadd_rn(v0, __fmul_rn(a0.x, b0.x));
        v1 = __fadd_rn(v1, __fmul_rn(a0.y, b0.y));
        v2 = __fadd_rn(v2, __fmul_rn(a0.z, b0.z));
        v3 = __fadd_rn(v3, __fmul_rn(a0.w, b0.w));
    }
    return __fadd_rn(__fadd_rn(v0, v1), __fadd_rn(v2, v3));
}

// ---------------------------------------------------------------------------
// K1: Bnp[k] = np-exact sum(cb[k]**2); Bnpb[k] = bf16(Bnp[k]) (RNE).
// bf16 keeps stageA's LDS copy at 8KB (occupancy!); ulp at 1.5e-5 is ~3e-8.
__global__ void bnp_kernel(const float* __restrict__ cb, float* __restrict__ Bnp,
                           unsigned short* __restrict__ Bnpb) {
    int k = blockIdx.x * 256 + threadIdx.x;
    if (k < NE) {
        float s = np_sumsq256(cb + (size_t)k * D);
        Bnp[k] = s;
        unsigned u = __float_as_uint(s);
        Bnpb[k] = (unsigned short)((u + 0x7FFFu + ((u >> 16) & 1u)) >> 16);  // RNE
    }
}

// K2: fp32 -> fp16 (RNE) with exact pow2 scale (cb2 = f16(4096*cb)).
__global__ void tof16_kernel(const float* __restrict__ x,
                             unsigned short* __restrict__ y, float scale, int n4) {
    int t = blockIdx.x * 256 + threadIdx.x;
    if (t >= n4) return;
    float4 v = *(const float4*)(x + (size_t)t * 4);
    ushort4 o;
    o.x = __half_as_ushort(__float2half_rn(v.x * scale));
    o.y = __half_as_ushort(__float2half_rn(v.y * scale));
    o.z = __half_as_ushort(__float2half_rn(v.z * scale));
    o.w = __half_as_ushort(__float2half_rn(v.w * scale));
    *(ushort4*)(y + (size_t)t * 4) = o;
}

// direct global->LDS 16B (dwordx4). LDS dest must be wave-uniform base;
// HW writes lane i at base + 16*i. Global source is per-lane.
__device__ __forceinline__ void gload_lds16(const void* g, void* l) {
    __builtin_amdgcn_global_load_lds(
        (const __attribute__((address_space(1))) unsigned int*)g,
        (__attribute__((address_space(3))) unsigned int*)l, 16, 0, 0);
}

// ---------------------------------------------------------------------------
// K3 (stage A): single-pass fp16 MFMA score GEMM + per-row top-2.
// acc = f16(z) · f16(4096*cb) ;  s = Bnp[k] - 2^-11 * acc.
// Block: 256 thr = 4 waves (2x2), tile 64 rows x 128 codes, wave 32x64
// (mt=2, nt=4 -- round-3 proven shape: 84 VGPR).
//   A: fp32 z converted to fp16 regs on the fly in the prologue.
//   B: 4 LDS buffers, prefetch distance 3, global_load_lds dwordx4,
//      counted-vmcnt barriers SYNC(4) (T3+T4): loads stay in flight ACROSS
//      barriers; loop body has no other VMEM so the vmcnt count is exact.
//   Bank swizzle: source seg ^= (code>>1)&3 pre-applied on the GLOBAL address
//      (LDS dest of gll must stay linear), same XOR on the ds_read side.
//   Occupancy: LDS = 8K (bf16 Bnp) + 32K (bufs) = 40960 B -> 4 blocks/CU,
//      exactly matching the 1024-block grid (4 blocks/CU co-resident).
__global__ __launch_bounds__(256, 4)
void stageA_f16(const float* __restrict__ z,
                const unsigned short* __restrict__ cb2,
                const unsigned short* __restrict__ Bnpb, int* __restrict__ idxArr,
                float* __restrict__ rowMin, unsigned long long* __restrict__ rowKey,
                int* __restrict__ flagCnt, int* __restrict__ flagList) {
    __shared__ unsigned char lds[8192 + 4 * 8192];   // bf16 Bnp 8K + 4 B-buffers
    unsigned short* BnpL = (unsigned short*)lds;
    unsigned short* Bt = (unsigned short*)(lds + 8192);

    const int tid  = threadIdx.x;
    const int wid  = tid >> 6;
    const int lane = tid & 63;
    const int ln   = lane & 15;      // col within 16x16 tile
    const int qd   = lane >> 4;      // quad
    const int wm   = wid & 1;        // wave row (32 rows each)
    const int wn   = wid >> 1;       // wave col (64 codes each)
    const int R0   = blockIdx.x * MT;

    // ---- Bnp(bf16) -> LDS (4096 ushort, 2 x 16B per thread)
    #pragma unroll
    for (int i = 0; i < 2; ++i) {
        int j = tid + 256 * i;
        *(uint4*)(BnpL + j * 8) = *(const uint4*)(Bnpb + j * 8);
    }

    // ---- A panel -> registers (fp32 -> fp16 RNE on the fly)
    f16x8 fa[8][2];
    {
        const float* za = z + (size_t)(R0 + wm * 32 + ln) * 256 + qd * 8;
        #pragma unroll
        for (int kc = 0; kc < 8; ++kc)
            #pragma unroll
            for (int mt = 0; mt < 2; ++mt) {
                const float* p = za + mt * 16 * 256 + kc * 32;
                float4 a = *(const float4*)p, b = *(const float4*)(p + 4);
                f16x8 h;
                h[0] = (_Float16)a.x; h[1] = (_Float16)a.y;
                h[2] = (_Float16)a.z; h[3] = (_Float16)a.w;
                h[4] = (_Float16)b.x; h[5] = (_Float16)b.y;
                h[6] = (_Float16)b.z; h[7] = (_Float16)b.w;
                fa[kc][mt] = h;
            }
    }

    // ---- B staging map (verified swizzle): lane l of gll j writes slot
    // wid*128 + j*64 + l -> code = wid*32 + j*16 + (l>>2), qslot = l&3.
    // Source seg = qslot ^ ((code>>1)&3) (same for code and code+16).
    const int cA  = wid * 32 + (lane >> 2);
    const int sgA = (lane & 3) ^ ((cA >> 1) & 3);
    const unsigned short* srcA = cb2 + cA * 256 + sgA * 8;
    unsigned short* dstW = Bt + wid * 1024;          // wave-uniform
    // B fragment ds_read byte offset within one buffer (swizzled read side)
    const int boffs = ((wn * 64 + ln) << 6) + ((qd ^ ((ln >> 1) & 3)) << 4);
    const unsigned char* btb = (const unsigned char*)Bt;

    float best1[8], best2[8];
    int   bidx[8];
    #pragma unroll
    for (int i = 0; i < 8; ++i) { best1[i] = FLT_MAX; best2[i] = FLT_MAX; bidx[i] = 0; }

    // ---- prologue: stage steps 0,1,2 into bufs 0,1,2; drain once.
    #pragma unroll
    for (int s = 0; s < 3; ++s) {
        gload_lds16(srcA + s * 32, dstW + s * 4096);
        gload_lds16(srcA + s * 32 + 4096, dstW + s * 4096 + 512);
    }
    __syncthreads();

    // ---- main loop: steps s = ct*8+kc; buf(s) = kc&3; issue s+3 each step.
    for (int ct = 0; ct < 31; ++ct) {
        f32x4 acc[2][4];
        #pragma unroll
        for (int i = 0; i < 2; ++i)
            #pragma unroll
            for (int j = 0; j < 4; ++j) acc[i][j] = (f32x4){0.f, 0.f, 0.f, 0.f};

        #pragma unroll
        for (int kc = 0; kc < 8; ++kc) {
            SYNC(4);    // buf kc&3 ready; prior readers of buf (kc+3)&3 done
            {           // issue step s+3
                const int s3k = kc + 3;
                int off = (ct + (s3k >> 3)) * 32768 + (s3k & 7) * 32;
                unsigned short* d = dstW + ((s3k & 3) << 12);
                gload_lds16(srcA + off, d);
                gload_lds16(srcA + off + 4096, d + 512);
            }
            f16x8 fb[4];
            #pragma unroll
            for (int nt = 0; nt < 4; ++nt)
                fb[nt] = *(const f16x8*)(btb + ((kc & 3) << 13) + boffs + nt * 1024);
            __builtin_amdgcn_s_setprio(1);
            #pragma unroll
            for (int mt = 0; mt < 2; ++mt)
                #pragma unroll
                for (int nt = 0; nt < 4; ++nt)
                    acc[mt][nt] = __builtin_amdgcn_mfma_f32_16x16x32_f16(
                        fa[kc][mt], fb[nt], acc[mt][nt], 0, 0, 0);
            __builtin_amdgcn_s_setprio(0);

            if (kc == 7) {   // epilogue: fold scores into per-lane top-2
                const int C0 = ct * 128;
                #pragma unroll
                for (int nt = 0; nt < 4; ++nt) {
                    int col = C0 + wn * 64 + nt * 16 + ln;
                    float bn = __uint_as_float(((unsigned)BnpL[col]) << 16);
                    #pragma unroll
                    for (int mt = 0; mt < 2; ++mt) {
                        f32x4 a = acc[mt][nt];
                        #pragma unroll
                        for (int r = 0; r < 4; ++r) {
                            float s = fmaf(-4.8828125e-4f, a[r], bn);   // -2^-11
                            int ii = mt * 4 + r;
                            bool lt = s < best1[ii];
                            best2[ii] = __builtin_amdgcn_fmed3f(best1[ii], best2[ii], s);
                            bidx[ii]  = lt ? col : bidx[ii];
                            best1[ii] = fminf(best1[ii], s);
                        }
                    }
                }
            }
        }
    }
    // ---- tail ct = 31 (steps 248..255): wind down the pipeline.
    {
        const int ct = 31;
        f32x4 acc[2][4];
        #pragma unroll
        for (int i = 0; i < 2; ++i)
            #pragma unroll
            for (int j = 0; j < 4; ++j) acc[i][j] = (f32x4){0.f, 0.f, 0.f, 0.f};

        #pragma unroll
        for (int kc = 0; kc < 8; ++kc) {
            if (kc <= 5) { SYNC(4); } else if (kc == 6) { SYNC(2); } else { SYNC(0); }
            if (kc <= 4) {
                const int s3k = kc + 3;
                int off = ct * 32768 + (s3k & 7) * 32;
                unsigned short* d = dstW + ((s3k & 3) << 12);
                gload_lds16(srcA + off, d);
                gload_lds16(srcA + off + 4096, d + 512);
            }
            f16x8 fb[4];
            #pragma unroll
            for (int nt = 0; nt < 4; ++nt)
                fb[nt] = *(const f16x8*)(btb + ((kc & 3) << 13) + boffs + nt * 1024);
            __builtin_amdgcn_s_setprio(1);
            #pragma unroll
            for (int mt = 0; mt < 2; ++mt)
                #pragma unroll
                for (int nt = 0; nt < 4; ++nt)
                    acc[mt][nt] = __builtin_amdgcn_mfma_f32_16x16x32_f16(
                        fa[kc][mt], fb[nt], acc[mt][nt], 0, 0, 0);
            __builtin_amdgcn_s_setprio(0);

            if (kc == 7) {
                const int C0 = ct * 128;
                #pragma unroll
                for (int nt = 0; nt < 4; ++nt) {
                    int col = C0 + wn * 64 + nt * 16 + ln;
                    float bn = __uint_as_float(((unsigned)BnpL[col]) << 16);
                    #pragma unroll
                    for (int mt = 0; mt < 2; ++mt) {
                        f32x4 a = acc[mt][nt];
                        #pragma unroll
                        for (int r = 0; r < 4; ++r) {
                            float s = fmaf(-4.8828125e-4f, a[r], bn);
                            int ii = mt * 4 + r;
                            bool lt = s < best1[ii];
                            best2[ii] = __builtin_amdgcn_fmed3f(best1[ii], best2[ii], s);
                            bidx[ii]  = lt ? col : bidx[ii];
                            best1[ii] = fminf(best1[ii], s);
                        }
                    }
                }
            }
        }
    }

    // merge across the 16 ln-lanes (same rows, different cols); '<'+idx keeps np rule
    #pragma unroll
    for (int mask = 1; mask < 16; mask <<= 1) {
        #pragma unroll
        for (int ii = 0; ii < 8; ++ii) {
            float c1 = __shfl_xor(best1[ii], mask);
            float c2 = __shfl_xor(best2[ii], mask);
            int   ci = __shfl_xor(bidx[ii], mask);
            if (c1 < best1[ii] || (c1 == best1[ii] && ci < bidx[ii])) {
                best2[ii] = fminf(best1[ii], c2);
                best1[ii] = c1; bidx[ii] = ci;
            } else {
                best2[ii] = fminf(best2[ii], c1);
            }
        }
    }
    __syncthreads();   // reuse LDS (Bnp area) for cross-wave merge
    float* mb1 = (float*)lds;          // [64][2]
    float* mb2 = mb1 + 128;
    int*   mix = (int*)(mb2 + 128);
    if (ln == 0) {
        #pragma unroll
        for (int mt = 0; mt < 2; ++mt)
            #pragma unroll
            for (int r = 0; r < 4; ++r) {
                int row = wm * 32 + mt * 16 + qd * 4 + r;
                mb1[row * 2 + wn] = best1[mt * 4 + r];
                mb2[row * 2 + wn] = best2[mt * 4 + r];
                mix[row * 2 + wn] = bidx[mt * 4 + r];
            }
    }
    __syncthreads();
    if (tid < MT) {
        int r = tid;
        float b1 = mb1[r * 2], b2v = mb2[r * 2]; int ix = mix[r * 2];
        float c1 = mb1[r * 2 + 1], c2 = mb2[r * 2 + 1]; int ci = mix[r * 2 + 1];
        if (c1 < b1 || (c1 == b1 && ci < ix)) { b2v = fminf(b1, c2); b1 = c1; ix = ci; }
        else b2v = fminf(b2v, c1);
        idxArr[R0 + r] = ix;
        rowMin[R0 + r] = b1;
        rowKey[R0 + r] = ~0ULL;
        if (b2v - b1 <= DELTA) {
            int p = atomicAdd(flagCnt, 1);
            flagList[p] = R0 + r;
        }
    }
}

// ---------------------------------------------------------------------------
// K4 (stage B): flagged-row rescan, SINGLE-PASS fp16 clone of stageA's score
// math (same staged cb2 bytes, same MFMA order, same fmaf; Bnp from f32 --
// both scores are within E of s_np).  Sufficiency: for the np-argmin k*,
//   s_B(k*) <= s_np(k*) + E <= s_np(kA) + E <= s_A(kA) + 2E = rowMin + 2E,
// and DELTA >= 2E by construction, so s <= rowMin + DELTA catches k* (and
// any np-tie).  stageC then rescores np-exactly.
// Block: 64 flagged rows x 128 codes per ct, 4 cts (512-code y-slice),
// wave shape mt=4/nt=2, 4-buffer SYNC(4) pipeline.
// Hits go to two 64-bit masks, emitted AFTER the loop (K-loop VMEM-pure).
__global__ __launch_bounds__(256, 2)
void stageB_f16(const float* __restrict__ z,
                const unsigned short* __restrict__ cb2,
                const float* __restrict__ Bnp, const float* __restrict__ rowMin,
                const int* __restrict__ flagCnt, const int* __restrict__ flagList,
                int* __restrict__ candCnt, unsigned int* __restrict__ candList) {
    __shared__ unsigned char lds[4 * 8192 + 512];    // 4 B-buffers + frow/rmin
    unsigned short* Bt = (unsigned short*)lds;
    int*   frow   = (int*)(lds + 32768);             // [64]
    float* rmin_l = (float*)(lds + 32768 + 256);     // [64]

    const int nf = *flagCnt;
    const int R0 = blockIdx.x * MT;
    if (R0 >= nf) return;
    const int m = min(MT, nf - R0);

    const int tid  = threadIdx.x;
    const int wid  = tid >> 6;
    const int lane = tid & 63;
    const int ln   = lane & 15;
    const int qd   = lane >> 4;
    const int wn   = wid;
    const int ktBeg = blockIdx.y * (NE / NSPLITB);   // 512 codes per y-block

    if (tid < MT) {
        int fr = flagList[R0 + min(tid, m - 1)];   // pad w/ last row (dups harmless)
        frow[tid] = fr;
        rmin_l[tid] = rowMin[fr];
    }
    __syncthreads();

    // per-lane rowMin for its 16 (mt,r) rows
    float rmv[16];
    #pragma unroll
    for (int mt = 0; mt < 4; ++mt)
        #pragma unroll
        for (int r = 0; r < 4; ++r)
            rmv[mt * 4 + r] = rmin_l[mt * 16 + qd * 4 + r];

    // Bnp for this block's code range -> regs (static indexing)
    float bnv[4][2];
    #pragma unroll
    for (int ct = 0; ct < 4; ++ct)
        #pragma unroll
        for (int nt = 0; nt < 2; ++nt)
            bnv[ct][nt] = Bnp[ktBeg + ct * 128 + wn * 32 + nt * 16 + ln];

    // A rows (gathered) -> fp16 regs on the fly; rows frow[mt*16 + ln]
    f16x8 fa[8][4];
    {
        int rA[4];
        #pragma unroll
        for (int mt = 0; mt < 4; ++mt) rA[mt] = frow[mt * 16 + ln];
        #pragma unroll
        for (int kc = 0; kc < 8; ++kc)
            #pragma unroll
            for (int mt = 0; mt < 4; ++mt) {
                const float* p = z + (size_t)rA[mt] * 256 + kc * 32 + qd * 8;
                float4 a = *(const float4*)p, b = *(const float4*)(p + 4);
                f16x8 h;
                h[0] = (_Float16)a.x; h[1] = (_Float16)a.y;
                h[2] = (_Float16)a.z; h[3] = (_Float16)a.w;
                h[4] = (_Float16)b.x; h[5] = (_Float16)b.y;
                h[6] = (_Float16)b.z; h[7] = (_Float16)b.w;
                fa[kc][mt] = h;
            }
    }

    // B staging map (same verified swizzle as stageA)
    const int cA  = wid * 32 + (lane >> 2);
    const int sgA = (lane & 3) ^ ((cA >> 1) & 3);
    const unsigned short* srcA = cb2 + (size_t)(ktBeg + cA) * 256 + sgA * 8;
    unsigned short* dstW = Bt + wid * 1024;
    const int boffs = ((wn * 32 + ln) << 6) + ((qd ^ ((ln >> 1) & 3)) << 4);
    const unsigned char* btb = (const unsigned char*)Bt;

    // prologue: stage steps 0,1,2 into bufs 0,1,2; drain once.
    #pragma unroll
    for (int s = 0; s < 3; ++s) {
        gload_lds16(srcA + s * 32, dstW + s * 4096);
        gload_lds16(srcA + s * 32 + 4096, dstW + s * 4096 + 512);
    }
    __syncthreads();

    unsigned long long hm0 = 0, hm1 = 0;   // bit = ((ct&1)<<5)|(nt<<4)|(mt<<2)|r

    #pragma unroll
    for (int ct = 0; ct < 4; ++ct) {
        f32x4 acc[4][2];
        #pragma unroll
        for (int i = 0; i < 4; ++i)
            #pragma unroll
            for (int j = 0; j < 2; ++j) acc[i][j] = (f32x4){0.f, 0.f, 0.f, 0.f};

        #pragma unroll
        for (int kc = 0; kc < 8; ++kc) {
            const int s = ct * 8 + kc;
            if (s <= 29) { SYNC(4); } else if (s == 30) { SYNC(2); } else { SYNC(0); }
            if (s <= 28) {
                const int s3 = s + 3;
                int off = (s3 >> 3) * 32768 + (s3 & 7) * 32;
                unsigned short* d = dstW + ((s3 & 3) << 12);
                gload_lds16(srcA + off, d);
                gload_lds16(srcA + off + 4096, d + 512);
            }
            f16x8 fb[2];
            #pragma unroll
            for (int nt = 0; nt < 2; ++nt)
                fb[nt] = *(const f16x8*)(btb + ((s & 3) << 13) + boffs + nt * 1024);
            __builtin_amdgcn_s_setprio(1);
            #pragma unroll
            for (int mt = 0; mt < 4; ++mt)
                #pragma unroll
                for (int nt = 0; nt < 2; ++nt)
                    acc[mt][nt] = __builtin_amdgcn_mfma_f32_16x16x32_f16(
                        fa[kc][mt], fb[nt], acc[mt][nt], 0, 0, 0);
            __builtin_amdgcn_s_setprio(0);

            if (kc == 7) {
                #pragma unroll
                for (int nt = 0; nt < 2; ++nt)
                    #pragma unroll
                    for (int mt = 0; mt < 4; ++mt) {
                        f32x4 a = acc[mt][nt];
                        #pragma unroll
                        for (int r = 0; r < 4; ++r) {
                            float sc = fmaf(-4.8828125e-4f, a[r], bnv[ct][nt]);
                            if (sc <= rmv[mt * 4 + r] + DELTA) {
                                unsigned long long bit =
                                    1ull << (((ct & 1) << 5) | (nt << 4) | (mt << 2) | r);
                                if (ct < 2) hm0 |= bit; else hm1 |= bit;
                            }
                        }
                    }
            }
        }
    }

    // rare-path emission (post-loop; VMEM allowed here)
    #pragma unroll
    for (int h = 0; h < 2; ++h) {
        unsigned long long hm = h ? hm1 : hm0;
        while (hm) {
            int b = __builtin_ctzll(hm);
            hm &= hm - 1;
            int ctb = h * 2 + (b >> 5);
            int ntb = (b >> 4) & 1, mtb = (b >> 2) & 3, rb = b & 3;
            int col = ktBeg + ctb * 128 + wn * 32 + ntb * 16 + ln;
            int row = frow[mtb * 16 + qd * 4 + rb];
            int p = atomicAdd(candCnt, 1);
            if (p < CAND_CAP)
                candList[p] = ((unsigned)row << 12) | (unsigned)col;
        }
    }
}

// ---------------------------------------------------------------------------
// K5 (stage C): bit-exact numpy score per candidate (||z||^2 computed inline),
// folded via atomicMin((fp32 bits << 32) | k) = np's min-then-lowest-idx rule.
__global__ void stageC(const float* __restrict__ z, const float* __restrict__ cb,
                       const float* __restrict__ Bnp,
                       const int* __restrict__ candCnt,
                       const unsigned int* __restrict__ candList,
                       unsigned long long* __restrict__ rowKey) {
    int c = blockIdx.x * 256 + threadIdx.x;
    int n = min(*candCnt, CAND_CAP);
    if (c >= n) return;
    unsigned e = candList[c];
    int r = (int)(e >> 12);
    int k = (int)(e & 4095u);
    float Anp = np_sumsq256(z + (size_t)r * D);
    float C   = np_einsum_dot256(z + (size_t)r * D, cb + (size_t)k * D);
    float AB  = __fadd_rn(Anp, Bnp[k]);
    float s   = __fsub_rn(AB, __fadd_rn(C, C));
    unsigned long long key = ((unsigned long long)__float_as_uint(s) << 32) | (unsigned)k;
    atomicMin(rowKey + r, key);
}

// ---------------------------------------------------------------------------
// K6: gather out[r] = cb[idx]; idx from rowKey override (flagged) or idxArr.
__global__ void gather_kernel(const float* __restrict__ cb,
                              const int* __restrict__ idxArr,
                              const unsigned long long* __restrict__ rowKey,
                              float* __restrict__ out) {
    int r = blockIdx.x * 4 + (threadIdx.x >> 6);
    int l = threadIdx.x & 63;
    unsigned long long kv = rowKey[r];
    int ix = (kv != ~0ULL) ? (int)(kv & 0xFFFFFFFFull) : idxArr[r];
    *(float4*)(out + (size_t)r * D + l * 4) =
        *(const float4*)(cb + (size_t)ix * D + l * 4);
}

// ---------------------------------------------------------------------------
extern "C" void kernel_launch(void* const* d_in, const int* in_sizes, int n_in,
                              void* d_out, int out_size, void* d_ws, size_t ws_size,
                              hipStream_t stream) {
    const float* z  = (const float*)d_in[0];
    const float* cb = (const float*)d_in[1];
    float* out = (float*)d_out;
    const int nRows = in_sizes[0] / D;   // 65536

    char* w = (char*)d_ws;
    unsigned short* cb2 = (unsigned short*)w;                         // 2 MB
    unsigned long long* rowKey = (unsigned long long*)(w + 2097152);  // 512 KB
    int*   idxArr   = (int*)  (w + 2621440);                          // 256 KB
    float* rowMin   = (float*)(w + 2883584);                          // 256 KB
    int*   flagList = (int*)  (w + 3145728);                          // 256 KB
    float* Bnp      = (float*)(w + 3407872);                          // 16 KB
    unsigned short* Bnpb = (unsigned short*)(w + 3424256);            // 8 KB
    unsigned int* candList = (unsigned int*)(w + 3432448);            // 512 KB
    int*   flagCnt  = (int*)  (w + 3956736);
    int*   candCnt  = flagCnt + 1;

    hipMemsetAsync(flagCnt, 0, 8, stream);
    bnp_kernel<<<NE / 256, 256, 0, stream>>>(cb, Bnp, Bnpb);
    tof16_kernel<<<NE * D / 4 / 256, 256, 0, stream>>>(cb, cb2, 4096.0f, NE * D / 4);
    stageA_f16<<<nRows / MT, 256, 0, stream>>>(z, cb2, Bnpb, idxArr, rowMin,
                                               rowKey, flagCnt, flagList);
    stageB_f16<<<dim3(nRows / MT, NSPLITB), 256, 0, stream>>>(z, cb2, Bnp, rowMin,
                                                              flagCnt, flagList,
                                                              candCnt, candList);
    stageC<<<CAND_CAP / 256, 256, 0, stream>>>(z, cb, Bnp, candCnt, candList, rowKey);
    gather_kernel<<<nRows / 4, 256, 0, stream>>>(cb, idxArr, rowKey, out);
}

// Round 6
// 438.442 us; speedup vs baseline: 1.2617x; 1.2617x over previous
//
#include <hip/hip_runtime.h>
#include <hip/hip_fp16.h>
#include <cfloat>
#include <climits>

// VectorQuantizer2: z [32,2048,256] fp32, codebook [4096,256] fp32.
#define D     256
#define NE    4096
#define MT    64       // rows per block (stageA and stageB)
#define NSPLITB 8      // stageB K-split factor (512 codes per y-block)
// DELTA covers worst-case np fp32 envelope (2*4.6e-5) + fp16 single-pass dot
// worst bound (~5e-5 score) + bf16-Bnp quantization (~3e-8, negligible).
// DELTA >= 2*E_singlepass, the condition under which the single-pass stageB
// rescan is sufficient (see K4).
#define DELTA     1.5e-4f
#define CAND_CAP  131072

typedef _Float16 f16x8 __attribute__((ext_vector_type(8)));
typedef __attribute__((ext_vector_type(4))) float f32x4;

// counted-vmcnt barrier: keep prefetch in flight across the barrier (T4).
// Fused in ONE asm so no memory op can slip between wait and barrier.
// sched_barrier(0) after it pins every LDS read AFTER the wait (rule-18 class).
#define SYNC(n) do { \
    asm volatile("s_waitcnt vmcnt(" #n ")\n\ts_barrier" ::: "memory"); \
    __builtin_amdgcn_sched_barrier(0); \
} while (0)

// ---------------------------------------------------------------------------
// numpy-bit-exact fp32 helpers. __fmul_rn/__fadd_rn are contraction barriers.
__device__ __forceinline__ float np_block128_sq(const float* __restrict__ p) {
    float r[8];
    #pragma unroll
    for (int j = 0; j < 8; ++j) r[j] = __fmul_rn(p[j], p[j]);
    #pragma unroll
    for (int i = 8; i < 128; i += 8)
        #pragma unroll
        for (int j = 0; j < 8; ++j) r[j] = __fadd_rn(r[j], __fmul_rn(p[i + j], p[i + j]));
    return __fadd_rn(__fadd_rn(__fadd_rn(r[0], r[1]), __fadd_rn(r[2], r[3])),
                     __fadd_rn(__fadd_rn(r[4], r[5]), __fadd_rn(r[6], r[7])));
}
__device__ __forceinline__ float np_sumsq256(const float* __restrict__ p) {
    return __fadd_rn(np_block128_sq(p), np_block128_sq(p + 128));
}
// np.einsum('nd,kd->nk', optimize=False) dot: SSE 4-lane, no FMA, 16/iter,
// chained muladd order p3,p2,p1,p0, SSE3 hadd (v0+v1)+(v2+v3).
__device__ __forceinline__ float np_einsum_dot256(const float* __restrict__ zr,
                                                  const float* __restrict__ er) {
    float v0 = 0.f, v1 = 0.f, v2 = 0.f, v3 = 0.f;
    for (int t = 0; t < 256; t += 16) {
        float4 a0 = *(const float4*)(zr + t);
        float4 a1 = *(const float4*)(zr + t + 4);
        float4 a2 = *(const float4*)(zr + t + 8);
        float4 a3 = *(const float4*)(zr + t + 12);
        float4 b0 = *(const float4*)(er + t);
        float4 b1 = *(const float4*)(er + t + 4);
        float4 b2 = *(const float4*)(er + t + 8);
        float4 b3 = *(const float4*)(er + t + 12);
        v0 = __fadd_rn(v0, __fmul_rn(a3.x, b3.x));
        v1 = __fadd_rn(v1, __fmul_rn(a3.y, b3.y));
        v2 = __fadd_rn(v2, __fmul_rn(a3.z, b3.z));
        v3 = __fadd_rn(v3, __fmul_rn(a3.w, b3.w));
        v0 = __fadd_rn(v0, __fmul_rn(a2.x, b2.x));
        v1 = __fadd_rn(v1, __fmul_rn(a2.y, b2.y));
        v2 = __fadd_rn(v2, __fmul_rn(a2.z, b2.z));
        v3 = __fadd_rn(v3, __fmul_rn(a2.w, b2.w));
        v0 = __fadd_rn(v0, __fmul_rn(a1.x, b1.x));
        v1 = __fadd_rn(v1, __fmul_rn(a1.y, b1.y));
        v2 = __fadd_rn(v2, __fmul_rn(a1.z, b1.z));
        v3 = __fadd_rn(v3, __fmul_rn(a1.w, b1.w));
        v0 = __fadd_rn(v0, __fmul_rn(a0.x, b0.x));
        v1 = __fadd_rn(v1, __fmul_rn(a0.y, b0.y));
        v2 = __fadd_rn(v2, __fmul_rn(a0.z, b0.z));
        v3 = __fadd_rn(v3, __fmul_rn(a0.w, b0.w));
    }
    return __fadd_rn(__fadd_rn(v0, v1), __fadd_rn(v2, v3));
}

// ---------------------------------------------------------------------------
// K1: Bnp[k] = np-exact sum(cb[k]**2); Bnpb[k] = bf16(Bnp[k]) (RNE).
// bf16 keeps stageA's LDS copy at 8KB (occupancy!); ulp at 1.5e-5 is ~3e-8.
__global__ void bnp_kernel(const float* __restrict__ cb, float* __restrict__ Bnp,
                           unsigned short* __restrict__ Bnpb) {
    int k = blockIdx.x * 256 + threadIdx.x;
    if (k < NE) {
        float s = np_sumsq256(cb + (size_t)k * D);
        Bnp[k] = s;
        unsigned u = __float_as_uint(s);
        Bnpb[k] = (unsigned short)((u + 0x7FFFu + ((u >> 16) & 1u)) >> 16);  // RNE
    }
}

// K2: fp32 -> fp16 (RNE) with exact pow2 scale (cb2 = f16(4096*cb)).
__global__ void tof16_kernel(const float* __restrict__ x,
                             unsigned short* __restrict__ y, float scale, int n4) {
    int t = blockIdx.x * 256 + threadIdx.x;
    if (t >= n4) return;
    float4 v = *(const float4*)(x + (size_t)t * 4);
    ushort4 o;
    o.x = __half_as_ushort(__float2half_rn(v.x * scale));
    o.y = __half_as_ushort(__float2half_rn(v.y * scale));
    o.z = __half_as_ushort(__float2half_rn(v.z * scale));
    o.w = __half_as_ushort(__float2half_rn(v.w * scale));
    *(ushort4*)(y + (size_t)t * 4) = o;
}

// direct global->LDS 16B (dwordx4). LDS dest must be wave-uniform base;
// HW writes lane i at base + 16*i. Global source is per-lane.
__device__ __forceinline__ void gload_lds16(const void* g, void* l) {
    __builtin_amdgcn_global_load_lds(
        (const __attribute__((address_space(1))) unsigned int*)g,
        (__attribute__((address_space(3))) unsigned int*)l, 16, 0, 0);
}

// ---------------------------------------------------------------------------
// K3 (stage A): single-pass fp16 MFMA score GEMM + per-row top-2.
// acc = f16(z) · f16(4096*cb) ;  s = Bnp[k] - 2^-11 * acc.
// Block: 256 thr = 4 waves (2x2), tile 64 rows x 128 codes, wave 32x64
// (mt=2, nt=4 -- round-3 proven shape: 84 VGPR, zero spill).
//   A: fp32 z converted to fp16 regs on the fly in the prologue.
//   B: 4 LDS buffers, prefetch distance 3, global_load_lds dwordx4,
//      counted-vmcnt barriers SYNC(4) (T3+T4): loads stay in flight ACROSS
//      barriers; loop body has no other VMEM so the vmcnt count is exact.
//   Bank swizzle: source seg ^= (code>>1)&3 pre-applied on the GLOBAL address
//      (LDS dest of gll must stay linear), same XOR on the ds_read side.
//   Occupancy: LDS = 8K (bf16 Bnp) + 32K (bufs) = 40960 B -> 4 blocks/CU
//      purely LDS-limited.  __launch_bounds__ stays at 3: round-5 showed
//      (256,4) caps the allocator at 64 VGPR and spills fa/acc to scratch
//      (FETCH 45->440 MB, dur +70%).  At 84 VGPR the VGPR limit is 6
//      waves/SIMD, so LDS alone sets 4 blocks/CU.
__global__ __launch_bounds__(256, 3)
void stageA_f16(const float* __restrict__ z,
                const unsigned short* __restrict__ cb2,
                const unsigned short* __restrict__ Bnpb, int* __restrict__ idxArr,
                float* __restrict__ rowMin, unsigned long long* __restrict__ rowKey,
                int* __restrict__ flagCnt, int* __restrict__ flagList) {
    __shared__ unsigned char lds[8192 + 4 * 8192];   // bf16 Bnp 8K + 4 B-buffers
    unsigned short* BnpL = (unsigned short*)lds;
    unsigned short* Bt = (unsigned short*)(lds + 8192);

    const int tid  = threadIdx.x;
    const int wid  = tid >> 6;
    const int lane = tid & 63;
    const int ln   = lane & 15;      // col within 16x16 tile
    const int qd   = lane >> 4;      // quad
    const int wm   = wid & 1;        // wave row (32 rows each)
    const int wn   = wid >> 1;       // wave col (64 codes each)
    const int R0   = blockIdx.x * MT;

    // ---- Bnp(bf16) -> LDS (4096 ushort, 2 x 16B per thread)
    #pragma unroll
    for (int i = 0; i < 2; ++i) {
        int j = tid + 256 * i;
        *(uint4*)(BnpL + j * 8) = *(const uint4*)(Bnpb + j * 8);
    }

    // ---- A panel -> registers (fp32 -> fp16 RNE on the fly)
    f16x8 fa[8][2];
    {
        const float* za = z + (size_t)(R0 + wm * 32 + ln) * 256 + qd * 8;
        #pragma unroll
        for (int kc = 0; kc < 8; ++kc)
            #pragma unroll
            for (int mt = 0; mt < 2; ++mt) {
                const float* p = za + mt * 16 * 256 + kc * 32;
                float4 a = *(const float4*)p, b = *(const float4*)(p + 4);
                f16x8 h;
                h[0] = (_Float16)a.x; h[1] = (_Float16)a.y;
                h[2] = (_Float16)a.z; h[3] = (_Float16)a.w;
                h[4] = (_Float16)b.x; h[5] = (_Float16)b.y;
                h[6] = (_Float16)b.z; h[7] = (_Float16)b.w;
                fa[kc][mt] = h;
            }
    }

    // ---- B staging map (verified swizzle): lane l of gll j writes slot
    // wid*128 + j*64 + l -> code = wid*32 + j*16 + (l>>2), qslot = l&3.
    // Source seg = qslot ^ ((code>>1)&3) (same for code and code+16).
    const int cA  = wid * 32 + (lane >> 2);
    const int sgA = (lane & 3) ^ ((cA >> 1) & 3);
    const unsigned short* srcA = cb2 + cA * 256 + sgA * 8;
    unsigned short* dstW = Bt + wid * 1024;          // wave-uniform
    // B fragment ds_read byte offset within one buffer (swizzled read side)
    const int boffs = ((wn * 64 + ln) << 6) + ((qd ^ ((ln >> 1) & 3)) << 4);
    const unsigned char* btb = (const unsigned char*)Bt;

    float best1[8], best2[8];
    int   bidx[8];
    #pragma unroll
    for (int i = 0; i < 8; ++i) { best1[i] = FLT_MAX; best2[i] = FLT_MAX; bidx[i] = 0; }

    // ---- prologue: stage steps 0,1,2 into bufs 0,1,2; drain once.
    #pragma unroll
    for (int s = 0; s < 3; ++s) {
        gload_lds16(srcA + s * 32, dstW + s * 4096);
        gload_lds16(srcA + s * 32 + 4096, dstW + s * 4096 + 512);
    }
    __syncthreads();

    // ---- main loop: steps s = ct*8+kc; buf(s) = kc&3; issue s+3 each step.
    for (int ct = 0; ct < 31; ++ct) {
        f32x4 acc[2][4];
        #pragma unroll
        for (int i = 0; i < 2; ++i)
            #pragma unroll
            for (int j = 0; j < 4; ++j) acc[i][j] = (f32x4){0.f, 0.f, 0.f, 0.f};

        #pragma unroll
        for (int kc = 0; kc < 8; ++kc) {
            SYNC(4);    // buf kc&3 ready; prior readers of buf (kc+3)&3 done
            {           // issue step s+3
                const int s3k = kc + 3;
                int off = (ct + (s3k >> 3)) * 32768 + (s3k & 7) * 32;
                unsigned short* d = dstW + ((s3k & 3) << 12);
                gload_lds16(srcA + off, d);
                gload_lds16(srcA + off + 4096, d + 512);
            }
            f16x8 fb[4];
            #pragma unroll
            for (int nt = 0; nt < 4; ++nt)
                fb[nt] = *(const f16x8*)(btb + ((kc & 3) << 13) + boffs + nt * 1024);
            __builtin_amdgcn_s_setprio(1);
            #pragma unroll
            for (int mt = 0; mt < 2; ++mt)
                #pragma unroll
                for (int nt = 0; nt < 4; ++nt)
                    acc[mt][nt] = __builtin_amdgcn_mfma_f32_16x16x32_f16(
                        fa[kc][mt], fb[nt], acc[mt][nt], 0, 0, 0);
            __builtin_amdgcn_s_setprio(0);

            if (kc == 7) {   // epilogue: fold scores into per-lane top-2
                const int C0 = ct * 128;
                #pragma unroll
                for (int nt = 0; nt < 4; ++nt) {
                    int col = C0 + wn * 64 + nt * 16 + ln;
                    float bn = __uint_as_float(((unsigned)BnpL[col]) << 16);
                    #pragma unroll
                    for (int mt = 0; mt < 2; ++mt) {
                        f32x4 a = acc[mt][nt];
                        #pragma unroll
                        for (int r = 0; r < 4; ++r) {
                            float s = fmaf(-4.8828125e-4f, a[r], bn);   // -2^-11
                            int ii = mt * 4 + r;
                            bool lt = s < best1[ii];
                            best2[ii] = __builtin_amdgcn_fmed3f(best1[ii], best2[ii], s);
                            bidx[ii]  = lt ? col : bidx[ii];
                            best1[ii] = fminf(best1[ii], s);
                        }
                    }
                }
            }
        }
    }
    // ---- tail ct = 31 (steps 248..255): wind down the pipeline.
    {
        const int ct = 31;
        f32x4 acc[2][4];
        #pragma unroll
        for (int i = 0; i < 2; ++i)
            #pragma unroll
            for (int j = 0; j < 4; ++j) acc[i][j] = (f32x4){0.f, 0.f, 0.f, 0.f};

        #pragma unroll
        for (int kc = 0; kc < 8; ++kc) {
            if (kc <= 5) { SYNC(4); } else if (kc == 6) { SYNC(2); } else { SYNC(0); }
            if (kc <= 4) {
                const int s3k = kc + 3;
                int off = ct * 32768 + (s3k & 7) * 32;
                unsigned short* d = dstW + ((s3k & 3) << 12);
                gload_lds16(srcA + off, d);
                gload_lds16(srcA + off + 4096, d + 512);
            }
            f16x8 fb[4];
            #pragma unroll
            for (int nt = 0; nt < 4; ++nt)
                fb[nt] = *(const f16x8*)(btb + ((kc & 3) << 13) + boffs + nt * 1024);
            __builtin_amdgcn_s_setprio(1);
            #pragma unroll
            for (int mt = 0; mt < 2; ++mt)
                #pragma unroll
                for (int nt = 0; nt < 4; ++nt)
                    acc[mt][nt] = __builtin_amdgcn_mfma_f32_16x16x32_f16(
                        fa[kc][mt], fb[nt], acc[mt][nt], 0, 0, 0);
            __builtin_amdgcn_s_setprio(0);

            if (kc == 7) {
                const int C0 = ct * 128;
                #pragma unroll
                for (int nt = 0; nt < 4; ++nt) {
                    int col = C0 + wn * 64 + nt * 16 + ln;
                    float bn = __uint_as_float(((unsigned)BnpL[col]) << 16);
                    #pragma unroll
                    for (int mt = 0; mt < 2; ++mt) {
                        f32x4 a = acc[mt][nt];
                        #pragma unroll
                        for (int r = 0; r < 4; ++r) {
                            float s = fmaf(-4.8828125e-4f, a[r], bn);
                            int ii = mt * 4 + r;
                            bool lt = s < best1[ii];
                            best2[ii] = __builtin_amdgcn_fmed3f(best1[ii], best2[ii], s);
                            bidx[ii]  = lt ? col : bidx[ii];
                            best1[ii] = fminf(best1[ii], s);
                        }
                    }
                }
            }
        }
    }

    // merge across the 16 ln-lanes (same rows, different cols); '<'+idx keeps np rule
    #pragma unroll
    for (int mask = 1; mask < 16; mask <<= 1) {
        #pragma unroll
        for (int ii = 0; ii < 8; ++ii) {
            float c1 = __shfl_xor(best1[ii], mask);
            float c2 = __shfl_xor(best2[ii], mask);
            int   ci = __shfl_xor(bidx[ii], mask);
            if (c1 < best1[ii] || (c1 == best1[ii] && ci < bidx[ii])) {
                best2[ii] = fminf(best1[ii], c2);
                best1[ii] = c1; bidx[ii] = ci;
            } else {
                best2[ii] = fminf(best2[ii], c1);
            }
        }
    }
    __syncthreads();   // reuse LDS (Bnp area) for cross-wave merge
    float* mb1 = (float*)lds;          // [64][2]
    float* mb2 = mb1 + 128;
    int*   mix = (int*)(mb2 + 128);
    if (ln == 0) {
        #pragma unroll
        for (int mt = 0; mt < 2; ++mt)
            #pragma unroll
            for (int r = 0; r < 4; ++r) {
                int row = wm * 32 + mt * 16 + qd * 4 + r;
                mb1[row * 2 + wn] = best1[mt * 4 + r];
                mb2[row * 2 + wn] = best2[mt * 4 + r];
                mix[row * 2 + wn] = bidx[mt * 4 + r];
            }
    }
    __syncthreads();
    if (tid < MT) {
        int r = tid;
        float b1 = mb1[r * 2], b2v = mb2[r * 2]; int ix = mix[r * 2];
        float c1 = mb1[r * 2 + 1], c2 = mb2[r * 2 + 1]; int ci = mix[r * 2 + 1];
        if (c1 < b1 || (c1 == b1 && ci < ix)) { b2v = fminf(b1, c2); b1 = c1; ix = ci; }
        else b2v = fminf(b2v, c1);
        idxArr[R0 + r] = ix;
        rowMin[R0 + r] = b1;
        rowKey[R0 + r] = ~0ULL;
        if (b2v - b1 <= DELTA) {
            int p = atomicAdd(flagCnt, 1);
            flagList[p] = R0 + r;
        }
    }
}

// ---------------------------------------------------------------------------
// K4 (stage B): flagged-row rescan, SINGLE-PASS fp16 clone of stageA's score
// math (same staged cb2 bytes, same MFMA order, same fmaf; Bnp from f32 --
// both scores are within E of s_np).  Sufficiency: for the np-argmin k*,
//   s_B(k*) <= s_np(k*) + E <= s_np(kA) + E <= s_A(kA) + 2E = rowMin + 2E,
// and DELTA >= 2E by construction, so s <= rowMin + DELTA catches k* (and
// any np-tie).  stageC then rescores np-exactly.
// Block: 64 flagged rows x 128 codes per ct, 4 cts (512-code y-slice),
// wave shape mt=4/nt=2, 4-buffer SYNC(4) pipeline.
// Hits go to two 64-bit masks, emitted AFTER the loop (K-loop VMEM-pure).
__global__ __launch_bounds__(256, 2)
void stageB_f16(const float* __restrict__ z,
                const unsigned short* __restrict__ cb2,
                const float* __restrict__ Bnp, const float* __restrict__ rowMin,
                const int* __restrict__ flagCnt, const int* __restrict__ flagList,
                int* __restrict__ candCnt, unsigned int* __restrict__ candList) {
    __shared__ unsigned char lds[4 * 8192 + 512];    // 4 B-buffers + frow/rmin
    unsigned short* Bt = (unsigned short*)lds;
    int*   frow   = (int*)(lds + 32768);             // [64]
    float* rmin_l = (float*)(lds + 32768 + 256);     // [64]

    const int nf = *flagCnt;
    const int R0 = blockIdx.x * MT;
    if (R0 >= nf) return;
    const int m = min(MT, nf - R0);

    const int tid  = threadIdx.x;
    const int wid  = tid >> 6;
    const int lane = tid & 63;
    const int ln   = lane & 15;
    const int qd   = lane >> 4;
    const int wn   = wid;
    const int ktBeg = blockIdx.y * (NE / NSPLITB);   // 512 codes per y-block

    if (tid < MT) {
        int fr = flagList[R0 + min(tid, m - 1)];   // pad w/ last row (dups harmless)
        frow[tid] = fr;
        rmin_l[tid] = rowMin[fr];
    }
    __syncthreads();

    // per-lane rowMin for its 16 (mt,r) rows
    float rmv[16];
    #pragma unroll
    for (int mt = 0; mt < 4; ++mt)
        #pragma unroll
        for (int r = 0; r < 4; ++r)
            rmv[mt * 4 + r] = rmin_l[mt * 16 + qd * 4 + r];

    // Bnp for this block's code range -> regs (static indexing)
    float bnv[4][2];
    #pragma unroll
    for (int ct = 0; ct < 4; ++ct)
        #pragma unroll
        for (int nt = 0; nt < 2; ++nt)
            bnv[ct][nt] = Bnp[ktBeg + ct * 128 + wn * 32 + nt * 16 + ln];

    // A rows (gathered) -> fp16 regs on the fly; rows frow[mt*16 + ln]
    f16x8 fa[8][4];
    {
        int rA[4];
        #pragma unroll
        for (int mt = 0; mt < 4; ++mt) rA[mt] = frow[mt * 16 + ln];
        #pragma unroll
        for (int kc = 0; kc < 8; ++kc)
            #pragma unroll
            for (int mt = 0; mt < 4; ++mt) {
                const float* p = z + (size_t)rA[mt] * 256 + kc * 32 + qd * 8;
                float4 a = *(const float4*)p, b = *(const float4*)(p + 4);
                f16x8 h;
                h[0] = (_Float16)a.x; h[1] = (_Float16)a.y;
                h[2] = (_Float16)a.z; h[3] = (_Float16)a.w;
                h[4] = (_Float16)b.x; h[5] = (_Float16)b.y;
                h[6] = (_Float16)b.z; h[7] = (_Float16)b.w;
                fa[kc][mt] = h;
            }
    }

    // B staging map (same verified swizzle as stageA)
    const int cA  = wid * 32 + (lane >> 2);
    const int sgA = (lane & 3) ^ ((cA >> 1) & 3);
    const unsigned short* srcA = cb2 + (size_t)(ktBeg + cA) * 256 + sgA * 8;
    unsigned short* dstW = Bt + wid * 1024;
    const int boffs = ((wn * 32 + ln) << 6) + ((qd ^ ((ln >> 1) & 3)) << 4);
    const unsigned char* btb = (const unsigned char*)Bt;

    // prologue: stage steps 0,1,2 into bufs 0,1,2; drain once.
    #pragma unroll
    for (int s = 0; s < 3; ++s) {
        gload_lds16(srcA + s * 32, dstW + s * 4096);
        gload_lds16(srcA + s * 32 + 4096, dstW + s * 4096 + 512);
    }
    __syncthreads();

    unsigned long long hm0 = 0, hm1 = 0;   // bit = ((ct&1)<<5)|(nt<<4)|(mt<<2)|r

    #pragma unroll
    for (int ct = 0; ct < 4; ++ct) {
        f32x4 acc[4][2];
        #pragma unroll
        for (int i = 0; i < 4; ++i)
            #pragma unroll
            for (int j = 0; j < 2; ++j) acc[i][j] = (f32x4){0.f, 0.f, 0.f, 0.f};

        #pragma unroll
        for (int kc = 0; kc < 8; ++kc) {
            const int s = ct * 8 + kc;
            if (s <= 29) { SYNC(4); } else if (s == 30) { SYNC(2); } else { SYNC(0); }
            if (s <= 28) {
                const int s3 = s + 3;
                int off = (s3 >> 3) * 32768 + (s3 & 7) * 32;
                unsigned short* d = dstW + ((s3 & 3) << 12);
                gload_lds16(srcA + off, d);
                gload_lds16(srcA + off + 4096, d + 512);
            }
            f16x8 fb[2];
            #pragma unroll
            for (int nt = 0; nt < 2; ++nt)
                fb[nt] = *(const f16x8*)(btb + ((s & 3) << 13) + boffs + nt * 1024);
            __builtin_amdgcn_s_setprio(1);
            #pragma unroll
            for (int mt = 0; mt < 4; ++mt)
                #pragma unroll
                for (int nt = 0; nt < 2; ++nt)
                    acc[mt][nt] = __builtin_amdgcn_mfma_f32_16x16x32_f16(
                        fa[kc][mt], fb[nt], acc[mt][nt], 0, 0, 0);
            __builtin_amdgcn_s_setprio(0);

            if (kc == 7) {
                #pragma unroll
                for (int nt = 0; nt < 2; ++nt)
                    #pragma unroll
                    for (int mt = 0; mt < 4; ++mt) {
                        f32x4 a = acc[mt][nt];
                        #pragma unroll
                        for (int r = 0; r < 4; ++r) {
                            float sc = fmaf(-4.8828125e-4f, a[r], bnv[ct][nt]);
                            if (sc <= rmv[mt * 4 + r] + DELTA) {
                                unsigned long long bit =
                                    1ull << (((ct & 1) << 5) | (nt << 4) | (mt << 2) | r);
                                if (ct < 2) hm0 |= bit; else hm1 |= bit;
                            }
                        }
                    }
            }
        }
    }

    // rare-path emission (post-loop; VMEM allowed here)
    #pragma unroll
    for (int h = 0; h < 2; ++h) {
        unsigned long long hm = h ? hm1 : hm0;
        while (hm) {
            int b = __builtin_ctzll(hm);
            hm &= hm - 1;
            int ctb = h * 2 + (b >> 5);
            int ntb = (b >> 4) & 1, mtb = (b >> 2) & 3, rb = b & 3;
            int col = ktBeg + ctb * 128 + wn * 32 + ntb * 16 + ln;
            int row = frow[mtb * 16 + qd * 4 + rb];
            int p = atomicAdd(candCnt, 1);
            if (p < CAND_CAP)
                candList[p] = ((unsigned)row << 12) | (unsigned)col;
        }
    }
}

// ---------------------------------------------------------------------------
// K5 (stage C): bit-exact numpy score per candidate (||z||^2 computed inline),
// folded via atomicMin((fp32 bits << 32) | k) = np's min-then-lowest-idx rule.
__global__ void stageC(const float* __restrict__ z, const float* __restrict__ cb,
                       const float* __restrict__ Bnp,
                       const int* __restrict__ candCnt,
                       const unsigned int* __restrict__ candList,
                       unsigned long long* __restrict__ rowKey) {
    int c = blockIdx.x * 256 + threadIdx.x;
    int n = min(*candCnt, CAND_CAP);
    if (c >= n) return;
    unsigned e = candList[c];
    int r = (int)(e >> 12);
    int k = (int)(e & 4095u);
    float Anp = np_sumsq256(z + (size_t)r * D);
    float C   = np_einsum_dot256(z + (size_t)r * D, cb + (size_t)k * D);
    float AB  = __fadd_rn(Anp, Bnp[k]);
    float s   = __fsub_rn(AB, __fadd_rn(C, C));
    unsigned long long key = ((unsigned long long)__float_as_uint(s) << 32) | (unsigned)k;
    atomicMin(rowKey + r, key);
}

// ---------------------------------------------------------------------------
// K6: gather out[r] = cb[idx]; idx from rowKey override (flagged) or idxArr.
__global__ void gather_kernel(const float* __restrict__ cb,
                              const int* __restrict__ idxArr,
                              const unsigned long long* __restrict__ rowKey,
                              float* __restrict__ out) {
    int r = blockIdx.x * 4 + (threadIdx.x >> 6);
    int l = threadIdx.x & 63;
    unsigned long long kv = rowKey[r];
    int ix = (kv != ~0ULL) ? (int)(kv & 0xFFFFFFFFull) : idxArr[r];
    *(float4*)(out + (size_t)r * D + l * 4) =
        *(const float4*)(cb + (size_t)ix * D + l * 4);
}

// ---------------------------------------------------------------------------
extern "C" void kernel_launch(void* const* d_in, const int* in_sizes, int n_in,
                              void* d_out, int out_size, void* d_ws, size_t ws_size,
                              hipStream_t stream) {
    const float* z  = (const float*)d_in[0];
    const float* cb = (const float*)d_in[1];
    float* out = (float*)d_out;
    const int nRows = in_sizes[0] / D;   // 65536

    char* w = (char*)d_ws;
    unsigned short* cb2 = (unsigned short*)w;                         // 2 MB
    unsigned long long* rowKey = (unsigned long long*)(w + 2097152);  // 512 KB
    int*   idxArr   = (int*)  (w + 2621440);                          // 256 KB
    float* rowMin   = (float*)(w + 2883584);                          // 256 KB
    int*   flagList = (int*)  (w + 3145728);                          // 256 KB
    float* Bnp      = (float*)(w + 3407872);                          // 16 KB
    unsigned short* Bnpb = (unsigned short*)(w + 3424256);            // 8 KB
    unsigned int* candList = (unsigned int*)(w + 3432448);            // 512 KB
    int*   flagCnt  = (int*)  (w + 3956736);
    int*   candCnt  = flagCnt + 1;

    hipMemsetAsync(flagCnt, 0, 8, stream);
    bnp_kernel<<<NE / 256, 256, 0, stream>>>(cb, Bnp, Bnpb);
    tof16_kernel<<<NE * D / 4 / 256, 256, 0, stream>>>(cb, cb2, 4096.0f, NE * D / 4);
    stageA_f16<<<nRows / MT, 256, 0, stream>>>(z, cb2, Bnpb, idxArr, rowMin,
                                               rowKey, flagCnt, flagList);
    stageB_f16<<<dim3(nRows / MT, NSPLITB), 256, 0, stream>>>(z, cb2, Bnp, rowMin,
                                                              flagCnt, flagList,
                                                              candCnt, candList);
    stageC<<<CAND_CAP / 256, 256, 0, stream>>>(z, cb, Bnp, candCnt, candList, rowKey);
    gather_kernel<<<nRows / 4, 256, 0, stream>>>(cb, idxArr, rowKey, out);
}